// Round 1
// baseline (3814.935 us; speedup 1.0000x reference)
//
#include <hip/hip_runtime.h>
#include <hip/hip_bf16.h>
#include <cstddef>

// Problem constants
#define DIMC 1024
#define HC   16
#define DHC  64
#define LC   32
#define WC   8
#define EC   4
#define SEQC 4096
#define BC   4
#define BAND 16       // W + 2E
#define GCNT 512      // SEQ / W
#define MTOT 16384    // B * SEQ

// ---------------------------------------------------------------------------
// GEMM 1: out[r, n] = (X[r,:] @ Wm[:,n] + bias[n]) * scale
// X row r = (b*SEQ + s) maps to query[(s*B + b)*1024 + k]  (folds transpose)
// out layout: row-major (MTOT x N), N in {1024, 512}
// ---------------------------------------------------------------------------
__global__ __launch_bounds__(256) void gemm_in(const float* __restrict__ query,
    const float* __restrict__ Wm, const float* __restrict__ bias,
    float* __restrict__ out, int N, float scale) {
  __shared__ float As[16][65];
  __shared__ float Bs[16][64];
  int tid = threadIdx.x;
  int colBase = blockIdx.x * 64;
  int rowBase = blockIdx.y * 64;
  int tx = tid & 15, ty = tid >> 4;
  float acc[4][4] = {};
  for (int k0 = 0; k0 < 1024; k0 += 16) {
#pragma unroll
    for (int l = 0; l < 4; ++l) {
      int idx = l * 256 + tid;
      int i = idx >> 4, j = idx & 15;
      int r = rowBase + i;
      int bb = r >> 12, ss = r & 4095;
      As[j][i] = query[(size_t)((ss << 2) + bb) * 1024 + k0 + j];
    }
#pragma unroll
    for (int l = 0; l < 4; ++l) {
      int idx = l * 256 + tid;
      int kk = idx >> 6, n = idx & 63;
      Bs[kk][n] = Wm[(size_t)(k0 + kk) * N + colBase + n];
    }
    __syncthreads();
#pragma unroll
    for (int kk = 0; kk < 16; ++kk) {
      float a[4], bv[4];
#pragma unroll
      for (int ii = 0; ii < 4; ++ii) a[ii] = As[kk][ty * 4 + ii];
#pragma unroll
      for (int jj = 0; jj < 4; ++jj) bv[jj] = Bs[kk][tx * 4 + jj];
#pragma unroll
      for (int ii = 0; ii < 4; ++ii)
#pragma unroll
        for (int jj = 0; jj < 4; ++jj) acc[ii][jj] += a[ii] * bv[jj];
    }
    __syncthreads();
  }
#pragma unroll
  for (int ii = 0; ii < 4; ++ii) {
    int r = rowBase + ty * 4 + ii;
#pragma unroll
    for (int jj = 0; jj < 4; ++jj) {
      int c = colBase + tx * 4 + jj;
      out[(size_t)r * N + c] = (acc[ii][jj] + bias[c]) * scale;
    }
  }
}

// ---------------------------------------------------------------------------
// GEMM 2 (output projection): reads C (row-major b*SEQ+s), writes
// out[(s*B + b)*1024 + n] = C[r,:] @ Wo[:,n] + bo[n]
// ---------------------------------------------------------------------------
__global__ __launch_bounds__(256) void gemm_out(const float* __restrict__ cbuf,
    const float* __restrict__ Wm, const float* __restrict__ bias,
    float* __restrict__ out) {
  __shared__ float As[16][65];
  __shared__ float Bs[16][64];
  int tid = threadIdx.x;
  int colBase = blockIdx.x * 64;
  int rowBase = blockIdx.y * 64;
  int tx = tid & 15, ty = tid >> 4;
  float acc[4][4] = {};
  for (int k0 = 0; k0 < 1024; k0 += 16) {
#pragma unroll
    for (int l = 0; l < 4; ++l) {
      int idx = l * 256 + tid;
      int i = idx >> 4, j = idx & 15;
      As[j][i] = cbuf[(size_t)(rowBase + i) * 1024 + k0 + j];
    }
#pragma unroll
    for (int l = 0; l < 4; ++l) {
      int idx = l * 256 + tid;
      int kk = idx >> 6, n = idx & 63;
      Bs[kk][n] = Wm[(size_t)(k0 + kk) * 1024 + colBase + n];
    }
    __syncthreads();
#pragma unroll
    for (int kk = 0; kk < 16; ++kk) {
      float a[4], bv[4];
#pragma unroll
      for (int ii = 0; ii < 4; ++ii) a[ii] = As[kk][ty * 4 + ii];
#pragma unroll
      for (int jj = 0; jj < 4; ++jj) bv[jj] = Bs[kk][tx * 4 + jj];
#pragma unroll
      for (int ii = 0; ii < 4; ++ii)
#pragma unroll
        for (int jj = 0; jj < 4; ++jj) acc[ii][jj] += a[ii] * bv[jj];
    }
    __syncthreads();
  }
#pragma unroll
  for (int ii = 0; ii < 4; ++ii) {
    int r = rowBase + ty * 4 + ii;
    int ss = r & 4095, bb = r >> 12;
#pragma unroll
    for (int jj = 0; jj < 4; ++jj) {
      int c = colBase + tx * 4 + jj;
      out[(size_t)((ss << 2) + bb) * 1024 + c] = acc[ii][jj] + bias[c];
    }
  }
}

// ---------------------------------------------------------------------------
// In-place row LayerNorm over 1024 columns (16384 rows)
// ---------------------------------------------------------------------------
__global__ __launch_bounds__(256) void ln_rows(float* __restrict__ buf,
    const float* __restrict__ g, const float* __restrict__ b) {
  int row = blockIdx.x;
  float* p = buf + (size_t)row * 1024;
  int tid = threadIdx.x;
  float4 x = ((const float4*)p)[tid];
  float s = x.x + x.y + x.z + x.w;
  float ss = x.x * x.x + x.y * x.y + x.z * x.z + x.w * x.w;
#pragma unroll
  for (int off = 32; off > 0; off >>= 1) {
    s += __shfl_down(s, off);
    ss += __shfl_down(ss, off);
  }
  __shared__ float sred[8], ssred[8];
  int wave = tid >> 6, lane = tid & 63;
  if (lane == 0) { sred[wave] = s; ssred[wave] = ss; }
  __syncthreads();
  if (tid == 0) {
    float S = 0, SS = 0;
    for (int w = 0; w < 4; ++w) { S += sred[w]; SS += ssred[w]; }
    float m = S * (1.0f / 1024.0f);
    float v = SS * (1.0f / 1024.0f) - m * m;
    sred[0] = m;
    ssred[0] = rsqrtf(v + 1e-5f);
  }
  __syncthreads();
  float m = sred[0], rinv = ssred[0];
  float4 gg = ((const float4*)g)[tid];
  float4 bb = ((const float4*)b)[tid];
  float4 y;
  y.x = (x.x - m) * rinv * gg.x + bb.x;
  y.y = (x.y - m) * rinv * gg.y + bb.y;
  y.z = (x.z - m) * rinv * gg.z + bb.z;
  y.w = (x.w - m) * rinv * gg.w + bb.w;
  ((float4*)p)[tid] = y;
}

// ---------------------------------------------------------------------------
// Column softmax stats over s axis: for each (b, c) column of yd (b,s,512):
// stats[(b*512+c)*2] = max, [..+1] = 1/sum(exp(x-max))
// ---------------------------------------------------------------------------
__global__ __launch_bounds__(256) void col_stats(const float* __restrict__ yd,
    float* __restrict__ stats) {
  int bid = blockIdx.x;
  int b = bid >> 9, c = bid & 511;
  const float* base = yd + (size_t)b * 4096 * 512 + c;
  int tid = threadIdx.x;
  float mx = -1e30f;
  for (int s = tid; s < 4096; s += 256) mx = fmaxf(mx, base[(size_t)s * 512]);
#pragma unroll
  for (int off = 32; off > 0; off >>= 1) mx = fmaxf(mx, __shfl_down(mx, off));
  __shared__ float red[8];
  int wave = tid >> 6, lane = tid & 63;
  if (lane == 0) red[wave] = mx;
  __syncthreads();
  if (tid == 0) {
    float m = red[0];
    for (int w = 1; w < 4; ++w) m = fmaxf(m, red[w]);
    red[0] = m;
  }
  __syncthreads();
  mx = red[0];
  float sum = 0.f;
  for (int s = tid; s < 4096; s += 256) sum += expf(base[(size_t)s * 512] - mx);
#pragma unroll
  for (int off = 32; off > 0; off >>= 1) sum += __shfl_down(sum, off);
  __shared__ float red2[8];
  if (lane == 0) red2[wave] = sum;
  __syncthreads();
  if (tid == 0) {
    float S = 0;
    for (int w = 0; w < 4; ++w) S += red2[w];
    stats[(size_t)bid * 2] = mx;
    stats[(size_t)bid * 2 + 1] = 1.0f / S;
  }
}

// ---------------------------------------------------------------------------
// Landmark compression partials: Kc/Vc[b,l,h*64+d] partial over one s-chunk.
// grid (chunk=8, h=16, b=4), block 256 (d = tid&63, l-group = tid>>6 -> 8 l's)
// part layout: [chunk][b][h][l][d]
// ---------------------------------------------------------------------------
#define SCHUNK 512
__global__ __launch_bounds__(256) void compress(const float* __restrict__ yd,
    const float* __restrict__ stats, const float* __restrict__ kbuf,
    const float* __restrict__ vbuf, float* __restrict__ kcp,
    float* __restrict__ vcp) {
  int c = blockIdx.x, h = blockIdx.y, b = blockIdx.z;
  int tid = threadIdx.x;
  int d = tid & 63, lgp = tid >> 6;
  __shared__ float mxS[32], isS[32];
  __shared__ float pS[16][33];
  if (tid < 32) {
    mxS[tid] = stats[(size_t)(b * 512 + h * 32 + tid) * 2];
    isS[tid] = stats[(size_t)(b * 512 + h * 32 + tid) * 2 + 1];
  }
  __syncthreads();
  float accK[8] = {};
  float accV[8] = {};
  int s0 = c * SCHUNK;
  for (int sc = 0; sc < SCHUNK; sc += 16) {
#pragma unroll
    for (int l2 = 0; l2 < 2; ++l2) {
      int idx = l2 * 256 + tid;
      int sl = idx >> 5, l = idx & 31;
      float v = yd[((size_t)(b * 4096 + s0 + sc + sl)) * 512 + h * 32 + l];
      pS[sl][l] = expf(v - mxS[l]) * isS[l];
    }
    __syncthreads();
#pragma unroll 4
    for (int sl = 0; sl < 16; ++sl) {
      size_t roff = ((size_t)(b * 4096 + s0 + sc + sl)) * 1024 + h * 64 + d;
      float kv = kbuf[roff];
      float vv = vbuf[roff];
#pragma unroll
      for (int j = 0; j < 8; ++j) {
        float p = pS[sl][lgp * 8 + j];
        accK[j] += p * kv;
        accV[j] += p * vv;
      }
    }
    __syncthreads();
  }
#pragma unroll
  for (int j = 0; j < 8; ++j) {
    int l = lgp * 8 + j;
    size_t o = ((((size_t)c * 4 + b) * 16 + h) * 32 + l) * 64 + d;
    kcp[o] = accK[j];
    vcp[o] = accV[j];
  }
}

// ---------------------------------------------------------------------------
// Reduce compression partials (8 chunks) + LayerNorm over recombined 1024
// grid = 128 rows (b*32 + l), block 256. Writes kc_ln/vc_ln (b,l,1024)
// ---------------------------------------------------------------------------
__global__ __launch_bounds__(256) void ln_compress(const float* __restrict__ kcp,
    const float* __restrict__ vcp, const float* __restrict__ g_s,
    const float* __restrict__ b_s, float* __restrict__ kc_ln,
    float* __restrict__ vc_ln) {
  int row = blockIdx.x;
  int b = row >> 5, l = row & 31;
  int tid = threadIdx.x;
  __shared__ float xs[1024];
  __shared__ float red[8], red2[8];
  for (int t = 0; t < 2; ++t) {
    const float* part = t ? vcp : kcp;
    float* outp = t ? vc_ln : kc_ln;
    float lsum = 0, lss = 0;
#pragma unroll
    for (int q = 0; q < 4; ++q) {
      int j = q * 256 + tid;
      int h = j >> 6, d = j & 63;
      float x = 0;
      for (int cch = 0; cch < 8; ++cch)
        x += part[((((size_t)cch * 4 + b) * 16 + h) * 32 + l) * 64 + d];
      xs[j] = x;
      lsum += x;
      lss += x * x;
    }
#pragma unroll
    for (int off = 32; off > 0; off >>= 1) {
      lsum += __shfl_down(lsum, off);
      lss += __shfl_down(lss, off);
    }
    int wave = tid >> 6, lane = tid & 63;
    if (lane == 0) { red[wave] = lsum; red2[wave] = lss; }
    __syncthreads();
    if (tid == 0) {
      float S = 0, SS = 0;
      for (int w = 0; w < 4; ++w) { S += red[w]; SS += red2[w]; }
      float m = S * (1.0f / 1024.0f);
      float v = SS * (1.0f / 1024.0f) - m * m;
      red[0] = m;
      red2[0] = rsqrtf(v + 1e-5f);
    }
    __syncthreads();
    float m = red[0], rinv = red2[0];
#pragma unroll
    for (int q = 0; q < 4; ++q) {
      int j = q * 256 + tid;
      outp[(size_t)row * 1024 + j] = (xs[j] - m) * rinv * g_s[j] + b_s[j];
    }
    __syncthreads();
  }
}

// ---------------------------------------------------------------------------
// Fused attention: per (b,h,g): 8 queries x (32 compressed + 16 window keys).
// Writes C in place over the Q buffer (block owns its 8x64 slice exclusively).
// ---------------------------------------------------------------------------
__global__ __launch_bounds__(64) void attention(float* __restrict__ qc,
    const float* __restrict__ kbuf, const float* __restrict__ vbuf,
    const float* __restrict__ kc_ln, const float* __restrict__ vc_ln) {
  int g = blockIdx.x, h = blockIdx.y, b = blockIdx.z;
  int t = threadIdx.x;  // 0..63 = d
  __shared__ float KcS[32][64];
  __shared__ float VcS[32][64];
  __shared__ float qS[8][64];
  __shared__ float KwS[16][64];
  __shared__ float VwS[16][64];
  __shared__ float lgt[8][48];
  int s0 = g * 8;
#pragma unroll
  for (int l = 0; l < 32; ++l) {
    size_t o = ((size_t)(b * 32 + l)) * 1024 + h * 64 + t;
    KcS[l][t] = kc_ln[o];
    VcS[l][t] = vc_ln[o];
  }
#pragma unroll
  for (int w = 0; w < 8; ++w)
    qS[w][t] = qc[((size_t)(b * 4096 + s0 + w)) * 1024 + h * 64 + t];
#pragma unroll
  for (int k = 0; k < 16; ++k) {
    int pos = s0 - 4 + k;
    bool ok = (pos >= 0) && (pos < 4096);
    size_t o = ((size_t)(b * 4096 + pos)) * 1024 + h * 64 + t;
    KwS[k][t] = ok ? kbuf[o] : 0.f;
    VwS[k][t] = ok ? vbuf[o] : 0.f;
  }
  __syncthreads();
#pragma unroll
  for (int i = 0; i < 6; ++i) {
    int id = t * 6 + i;
    int w = id / 48, kk = id % 48;
    float acc = 0.f;
    if (kk < 32) {
      for (int j = 0; j < 64; ++j) acc += qS[w][j] * KcS[kk][j];
    } else {
      int k = kk - 32;
      int pos = s0 - 4 + k;
      if (pos >= 0 && pos < 4096) {
        for (int j = 0; j < 64; ++j) acc += qS[w][j] * KwS[k][j];
      } else {
        acc = -INFINITY;
      }
    }
    lgt[w][kk] = acc;
  }
  __syncthreads();
  if (t < 8) {
    float mx = -1e30f;
    for (int k = 0; k < 48; ++k) mx = fmaxf(mx, lgt[t][k]);
    float pv[48];
    float sum = 0.f;
    for (int k = 0; k < 48; ++k) { pv[k] = expf(lgt[t][k] - mx); sum += pv[k]; }
    float inv = 1.0f / sum;
    for (int k = 0; k < 48; ++k) lgt[t][k] = pv[k] * inv;
  }
  __syncthreads();
#pragma unroll
  for (int w = 0; w < 8; ++w) {
    float acc = 0.f;
    for (int l = 0; l < 32; ++l) acc += lgt[w][l] * VcS[l][t];
    for (int k = 0; k < 16; ++k) acc += lgt[w][32 + k] * VwS[k][t];
    qc[((size_t)(b * 4096 + s0 + w)) * 1024 + h * 64 + t] = acc;
  }
}

// ---------------------------------------------------------------------------
extern "C" void kernel_launch(void* const* d_in, const int* in_sizes, int n_in,
                              void* d_out, int out_size, void* d_ws,
                              size_t ws_size, hipStream_t stream) {
  const float* query = (const float*)d_in[0];
  const float* Wq = (const float*)d_in[1];
  const float* bq = (const float*)d_in[2];
  const float* Wk = (const float*)d_in[3];
  const float* bk = (const float*)d_in[4];
  const float* Wv = (const float*)d_in[5];
  const float* bv = (const float*)d_in[6];
  const float* Wo = (const float*)d_in[7];
  const float* bo = (const float*)d_in[8];
  const float* g_l = (const float*)d_in[9];
  const float* b_l = (const float*)d_in[10];
  const float* g_s = (const float*)d_in[11];
  const float* b_s = (const float*)d_in[12];
  const float* Wd = (const float*)d_in[13];
  const float* bd = (const float*)d_in[14];
  float* out = (float*)d_out;

  float* ws = (float*)d_ws;
  float* q_buf = ws;                       // 16777216  (Q, then C in-place)
  float* k_buf = q_buf + 16777216;         // 16777216
  float* v_buf = k_buf + 16777216;         // 16777216
  float* yd_buf = v_buf + 16777216;        // 8388608
  float* stats = yd_buf + 8388608;         // 4096
  float* kc_part = stats + 4096;           // 1048576
  float* vc_part = kc_part + 1048576;      // 1048576
  float* kc_ln = vc_part + 1048576;        // 131072
  float* vc_ln = kc_ln + 131072;           // 131072
  // total: 61,181,448 floats = ~233.4 MiB

  dim3 blk(256);
  // Projections (transpose of query folded into A addressing)
  gemm_in<<<dim3(16, 256), blk, 0, stream>>>(query, Wq, bq, q_buf, 1024, 0.125f);
  gemm_in<<<dim3(16, 256), blk, 0, stream>>>(query, Wk, bk, k_buf, 1024, 1.0f);
  gemm_in<<<dim3(16, 256), blk, 0, stream>>>(query, Wv, bv, v_buf, 1024, 1.0f);
  gemm_in<<<dim3(8, 256), blk, 0, stream>>>(query, Wd, bd, yd_buf, 512, 1.0f);
  // LayerNorm K, V (in place, row = (b,s), 1024 wide)
  ln_rows<<<16384, blk, 0, stream>>>(k_buf, g_l, b_l);
  ln_rows<<<16384, blk, 0, stream>>>(v_buf, g_l, b_l);
  // Column softmax stats over s axis
  col_stats<<<2048, blk, 0, stream>>>(yd_buf, stats);
  // Landmark compression (partials over 8 s-chunks), then reduce + LN
  compress<<<dim3(8, 16, 4), blk, 0, stream>>>(yd_buf, stats, k_buf, v_buf,
                                               kc_part, vc_part);
  ln_compress<<<128, blk, 0, stream>>>(kc_part, vc_part, g_s, b_s, kc_ln, vc_ln);
  // Fused 48-way attention; C overwrites q_buf
  attention<<<dim3(512, 16, 4), dim3(64), 0, stream>>>(q_buf, k_buf, v_buf,
                                                       kc_ln, vc_ln);
  // Output projection + (b,s)->(s,b) transpose
  gemm_out<<<dim3(16, 256), blk, 0, stream>>>(q_buf, Wo, bo, out);
}

// Round 2
// 3258.145 us; speedup vs baseline: 1.1709x; 1.1709x over previous
//
#include <hip/hip_runtime.h>
#include <hip/hip_bf16.h>
#include <cstddef>

// Problem constants
#define DIMC 1024
#define HC   16
#define DHC  64
#define LC   32
#define WC   8
#define EC   4
#define SEQC 4096
#define BC   4
#define BAND 16       // W + 2E
#define GCNT 512      // SEQ / W
#define MTOT 16384    // B * SEQ

// ---------------------------------------------------------------------------
// GEMM 1: out[r, n] = (X[r,:] @ Wm[:,n] + bias[n]) * scale
// X row r = (b*SEQ + s) maps to query[(s*B + b)*1024 + k]  (folds transpose)
// ---------------------------------------------------------------------------
__global__ __launch_bounds__(256) void gemm_in(const float* __restrict__ query,
    const float* __restrict__ Wm, const float* __restrict__ bias,
    float* __restrict__ out, int N, float scale) {
  __shared__ float As[16][65];
  __shared__ float Bs[16][64];
  int tid = threadIdx.x;
  int colBase = blockIdx.x * 64;
  int rowBase = blockIdx.y * 64;
  int tx = tid & 15, ty = tid >> 4;
  float acc[4][4] = {};
  for (int k0 = 0; k0 < 1024; k0 += 16) {
#pragma unroll
    for (int l = 0; l < 4; ++l) {
      int idx = l * 256 + tid;
      int i = idx >> 4, j = idx & 15;
      int r = rowBase + i;
      int bb = r >> 12, ss = r & 4095;
      As[j][i] = query[(size_t)((ss << 2) + bb) * 1024 + k0 + j];
    }
#pragma unroll
    for (int l = 0; l < 4; ++l) {
      int idx = l * 256 + tid;
      int kk = idx >> 6, n = idx & 63;
      Bs[kk][n] = Wm[(size_t)(k0 + kk) * N + colBase + n];
    }
    __syncthreads();
#pragma unroll
    for (int kk = 0; kk < 16; ++kk) {
      float a[4], bv[4];
#pragma unroll
      for (int ii = 0; ii < 4; ++ii) a[ii] = As[kk][ty * 4 + ii];
#pragma unroll
      for (int jj = 0; jj < 4; ++jj) bv[jj] = Bs[kk][tx * 4 + jj];
#pragma unroll
      for (int ii = 0; ii < 4; ++ii)
#pragma unroll
        for (int jj = 0; jj < 4; ++jj) acc[ii][jj] += a[ii] * bv[jj];
    }
    __syncthreads();
  }
#pragma unroll
  for (int ii = 0; ii < 4; ++ii) {
    int r = rowBase + ty * 4 + ii;
#pragma unroll
    for (int jj = 0; jj < 4; ++jj) {
      int c = colBase + tx * 4 + jj;
      out[(size_t)r * N + c] = (acc[ii][jj] + bias[c]) * scale;
    }
  }
}

// ---------------------------------------------------------------------------
// GEMM 2 (output projection): reads C (row-major b*SEQ+s), writes
// out[(s*B + b)*1024 + n] = C[r,:] @ Wo[:,n] + bo[n]
// ---------------------------------------------------------------------------
__global__ __launch_bounds__(256) void gemm_out(const float* __restrict__ cbuf,
    const float* __restrict__ Wm, const float* __restrict__ bias,
    float* __restrict__ out) {
  __shared__ float As[16][65];
  __shared__ float Bs[16][64];
  int tid = threadIdx.x;
  int colBase = blockIdx.x * 64;
  int rowBase = blockIdx.y * 64;
  int tx = tid & 15, ty = tid >> 4;
  float acc[4][4] = {};
  for (int k0 = 0; k0 < 1024; k0 += 16) {
#pragma unroll
    for (int l = 0; l < 4; ++l) {
      int idx = l * 256 + tid;
      int i = idx >> 4, j = idx & 15;
      As[j][i] = cbuf[(size_t)(rowBase + i) * 1024 + k0 + j];
    }
#pragma unroll
    for (int l = 0; l < 4; ++l) {
      int idx = l * 256 + tid;
      int kk = idx >> 6, n = idx & 63;
      Bs[kk][n] = Wm[(size_t)(k0 + kk) * 1024 + colBase + n];
    }
    __syncthreads();
#pragma unroll
    for (int kk = 0; kk < 16; ++kk) {
      float a[4], bv[4];
#pragma unroll
      for (int ii = 0; ii < 4; ++ii) a[ii] = As[kk][ty * 4 + ii];
#pragma unroll
      for (int jj = 0; jj < 4; ++jj) bv[jj] = Bs[kk][tx * 4 + jj];
#pragma unroll
      for (int ii = 0; ii < 4; ++ii)
#pragma unroll
        for (int jj = 0; jj < 4; ++jj) acc[ii][jj] += a[ii] * bv[jj];
    }
    __syncthreads();
  }
#pragma unroll
  for (int ii = 0; ii < 4; ++ii) {
    int r = rowBase + ty * 4 + ii;
    int ss = r & 4095, bb = r >> 12;
#pragma unroll
    for (int jj = 0; jj < 4; ++jj) {
      int c = colBase + tx * 4 + jj;
      out[(size_t)((ss << 2) + bb) * 1024 + c] = acc[ii][jj] + bias[c];
    }
  }
}

// ---------------------------------------------------------------------------
// In-place row LayerNorm over 1024 columns (16384 rows)
// ---------------------------------------------------------------------------
__global__ __launch_bounds__(256) void ln_rows(float* __restrict__ buf,
    const float* __restrict__ g, const float* __restrict__ b) {
  int row = blockIdx.x;
  float* p = buf + (size_t)row * 1024;
  int tid = threadIdx.x;
  float4 x = ((const float4*)p)[tid];
  float s = x.x + x.y + x.z + x.w;
  float ss = x.x * x.x + x.y * x.y + x.z * x.z + x.w * x.w;
#pragma unroll
  for (int off = 32; off > 0; off >>= 1) {
    s += __shfl_down(s, off);
    ss += __shfl_down(ss, off);
  }
  __shared__ float sred[8], ssred[8];
  int wave = tid >> 6, lane = tid & 63;
  if (lane == 0) { sred[wave] = s; ssred[wave] = ss; }
  __syncthreads();
  if (tid == 0) {
    float S = 0, SS = 0;
    for (int w = 0; w < 4; ++w) { S += sred[w]; SS += ssred[w]; }
    float m = S * (1.0f / 1024.0f);
    float v = SS * (1.0f / 1024.0f) - m * m;
    sred[0] = m;
    ssred[0] = rsqrtf(v + 1e-5f);
  }
  __syncthreads();
  float m = sred[0], rinv = ssred[0];
  float4 gg = ((const float4*)g)[tid];
  float4 bb = ((const float4*)b)[tid];
  float4 y;
  y.x = (x.x - m) * rinv * gg.x + bb.x;
  y.y = (x.y - m) * rinv * gg.y + bb.y;
  y.z = (x.z - m) * rinv * gg.z + bb.z;
  y.w = (x.w - m) * rinv * gg.w + bb.w;
  ((float4*)p)[tid] = y;
}

// ---------------------------------------------------------------------------
// Column softmax stats (online, single coalesced pass).
// grid (8 colgroups, 4 b), block 256: cols = cg*64 + lane, 4 row-strides.
// stats[(b*512+c)*2] = max, [..+1] = 1/sum(exp(x-max))
// ---------------------------------------------------------------------------
__global__ __launch_bounds__(256) void col_stats(const float* __restrict__ yd,
    float* __restrict__ stats) {
  int cg = blockIdx.x, b = blockIdx.y;
  int t = threadIdx.x;
  int lane = t & 63, grp = t >> 6;
  const float* base = yd + (size_t)b * 4096 * 512 + cg * 64 + lane;
  float m = -1e30f, s = 0.f;
  for (int r = grp; r < 4096; r += 4) {
    float x = base[(size_t)r * 512];
    float mn = fmaxf(m, x);
    s = s * expf(m - mn) + expf(x - mn);
    m = mn;
  }
  __shared__ float mS[4][64], sS[4][64];
  mS[grp][lane] = m;
  sS[grp][lane] = s;
  __syncthreads();
  if (grp == 0) {
    float M = mS[0][lane], S = sS[0][lane];
#pragma unroll
    for (int k = 1; k < 4; ++k) {
      float m2 = mS[k][lane], s2 = sS[k][lane];
      float Mn = fmaxf(M, m2);
      S = S * expf(M - Mn) + s2 * expf(m2 - Mn);
      M = Mn;
    }
    int col = cg * 64 + lane;
    stats[((size_t)(b * 512 + col)) * 2] = M;
    stats[((size_t)(b * 512 + col)) * 2 + 1] = 1.0f / S;
  }
}

// ---------------------------------------------------------------------------
// Landmark compression partials (unchanged)
// ---------------------------------------------------------------------------
#define SCHUNK 512
__global__ __launch_bounds__(256) void compress(const float* __restrict__ yd,
    const float* __restrict__ stats, const float* __restrict__ kbuf,
    const float* __restrict__ vbuf, float* __restrict__ kcp,
    float* __restrict__ vcp) {
  int c = blockIdx.x, h = blockIdx.y, b = blockIdx.z;
  int tid = threadIdx.x;
  int d = tid & 63, lgp = tid >> 6;
  __shared__ float mxS[32], isS[32];
  __shared__ float pS[16][33];
  if (tid < 32) {
    mxS[tid] = stats[(size_t)(b * 512 + h * 32 + tid) * 2];
    isS[tid] = stats[(size_t)(b * 512 + h * 32 + tid) * 2 + 1];
  }
  __syncthreads();
  float accK[8] = {};
  float accV[8] = {};
  int s0 = c * SCHUNK;
  for (int sc = 0; sc < SCHUNK; sc += 16) {
#pragma unroll
    for (int l2 = 0; l2 < 2; ++l2) {
      int idx = l2 * 256 + tid;
      int sl = idx >> 5, l = idx & 31;
      float v = yd[((size_t)(b * 4096 + s0 + sc + sl)) * 512 + h * 32 + l];
      pS[sl][l] = expf(v - mxS[l]) * isS[l];
    }
    __syncthreads();
#pragma unroll 4
    for (int sl = 0; sl < 16; ++sl) {
      size_t roff = ((size_t)(b * 4096 + s0 + sc + sl)) * 1024 + h * 64 + d;
      float kv = kbuf[roff];
      float vv = vbuf[roff];
#pragma unroll
      for (int j = 0; j < 8; ++j) {
        float p = pS[sl][lgp * 8 + j];
        accK[j] += p * kv;
        accV[j] += p * vv;
      }
    }
    __syncthreads();
  }
#pragma unroll
  for (int j = 0; j < 8; ++j) {
    int l = lgp * 8 + j;
    size_t o = ((((size_t)c * 4 + b) * 16 + h) * 32 + l) * 64 + d;
    kcp[o] = accK[j];
    vcp[o] = accV[j];
  }
}

// ---------------------------------------------------------------------------
// Reduce compression partials + LayerNorm (unchanged)
// ---------------------------------------------------------------------------
__global__ __launch_bounds__(256) void ln_compress(const float* __restrict__ kcp,
    const float* __restrict__ vcp, const float* __restrict__ g_s,
    const float* __restrict__ b_s, float* __restrict__ kc_ln,
    float* __restrict__ vc_ln) {
  int row = blockIdx.x;
  int b = row >> 5, l = row & 31;
  int tid = threadIdx.x;
  __shared__ float xs[1024];
  __shared__ float red[8], red2[8];
  for (int t = 0; t < 2; ++t) {
    const float* part = t ? vcp : kcp;
    float* outp = t ? vc_ln : kc_ln;
    float lsum = 0, lss = 0;
#pragma unroll
    for (int q = 0; q < 4; ++q) {
      int j = q * 256 + tid;
      int h = j >> 6, d = j & 63;
      float x = 0;
      for (int cch = 0; cch < 8; ++cch)
        x += part[((((size_t)cch * 4 + b) * 16 + h) * 32 + l) * 64 + d];
      xs[j] = x;
      lsum += x;
      lss += x * x;
    }
#pragma unroll
    for (int off = 32; off > 0; off >>= 1) {
      lsum += __shfl_down(lsum, off);
      lss += __shfl_down(lss, off);
    }
    int wave = tid >> 6, lane = tid & 63;
    if (lane == 0) { red[wave] = lsum; red2[wave] = lss; }
    __syncthreads();
    if (tid == 0) {
      float S = 0, SS = 0;
      for (int w = 0; w < 4; ++w) { S += red[w]; SS += red2[w]; }
      float m = S * (1.0f / 1024.0f);
      float v = SS * (1.0f / 1024.0f) - m * m;
      red[0] = m;
      red2[0] = rsqrtf(v + 1e-5f);
    }
    __syncthreads();
    float m = red[0], rinv = red2[0];
#pragma unroll
    for (int q = 0; q < 4; ++q) {
      int j = q * 256 + tid;
      outp[(size_t)row * 1024 + j] = (xs[j] - m) * rinv * g_s[j] + b_s[j];
    }
    __syncthreads();
  }
}

// ---------------------------------------------------------------------------
// Fused attention v2: 256 threads, 64 queries (8 groups) per block.
// All LDS tiles padded to stride 65 (conflict-free). Logits alias the Q tile.
// grid (64 qtiles, 16 h, 4 b). Writes C in place over q_buf.
// ---------------------------------------------------------------------------
__global__ __launch_bounds__(256) void attention(float* __restrict__ qc,
    const float* __restrict__ kbuf, const float* __restrict__ vbuf,
    const float* __restrict__ kc_ln, const float* __restrict__ vc_ln) {
  int qt = blockIdx.x, h = blockIdx.y, b = blockIdx.z;
  int t = threadIdx.x;
  // 65-stride tiles: Kc(32) Vc(32) Kw(72) Vw(72) Q/lgt(64)  = 272*65 floats
  __shared__ float smem[272 * 65];
  float* KcS = smem;               // 32 x 65
  float* VcS = KcS + 32 * 65;      // 32 x 65
  float* KwS = VcS + 32 * 65;      // 72 x 65
  float* VwS = KwS + 72 * 65;      // 72 x 65
  float* qS  = VwS + 72 * 65;      // 64 x 65 (later: logits 64 x 48)
  int s0 = qt * 64;
  int hoff = h * 64;
  // stage Kc/Vc (coalesced 64-wide)
#pragma unroll
  for (int it = 0; it < 8; ++it) {
    int idx = it * 256 + t;
    int l = idx >> 6, d = idx & 63;
    size_t o = ((size_t)(b * 32 + l)) * 1024 + hoff + d;
    KcS[l * 65 + d] = kc_ln[o];
    VcS[l * 65 + d] = vc_ln[o];
  }
  // stage Q (64 rows)
#pragma unroll
  for (int it = 0; it < 16; ++it) {
    int idx = it * 256 + t;
    int w = idx >> 6, d = idx & 63;
    qS[w * 65 + d] = qc[((size_t)(b * 4096 + s0 + w)) * 1024 + hoff + d];
  }
  // stage window K/V (72 rows: s0-4 .. s0+67)
#pragma unroll
  for (int it = 0; it < 18; ++it) {
    int idx = it * 256 + t;
    int r = idx >> 6, d = idx & 63;
    int pos = s0 - 4 + r;
    bool ok = (pos >= 0) && (pos < 4096);
    size_t o = ((size_t)(b * 4096 + pos)) * 1024 + hoff + d;
    KwS[r * 65 + d] = ok ? kbuf[o] : 0.f;
    VwS[r * 65 + d] = ok ? vbuf[o] : 0.f;
  }
  __syncthreads();
  // ---- logits: thread = (qi: 4 queries, ki: 3 keys) ----
  int qi = t & 15, ki = t >> 4;
  int g = qi >> 1;  // all 4 queries of this thread share group g
  float lr[4][3] = {};
#pragma unroll 8
  for (int j = 0; j < 64; ++j) {
    float a[4];
#pragma unroll
    for (int ii = 0; ii < 4; ++ii) a[ii] = qS[(qi * 4 + ii) * 65 + j];
    float bb[3];
#pragma unroll
    for (int c = 0; c < 3; ++c) {
      int kk = ki * 3 + c;
      bb[c] = (kk < 32) ? KcS[kk * 65 + j] : KwS[(g * 8 + kk - 32) * 65 + j];
    }
#pragma unroll
    for (int ii = 0; ii < 4; ++ii)
#pragma unroll
      for (int c = 0; c < 3; ++c) lr[ii][c] += a[ii] * bb[c];
  }
#pragma unroll
  for (int c = 0; c < 3; ++c) {
    int kk = ki * 3 + c;
    if (kk >= 32) {
      int pos = s0 + g * 8 - 4 + (kk - 32);
      if (pos < 0 || pos >= 4096) {
#pragma unroll
        for (int ii = 0; ii < 4; ++ii) lr[ii][c] = -INFINITY;
      }
    }
  }
  __syncthreads();  // all reads of qS done; safe to overwrite with logits
  float* lgt = qS;  // 64 rows x 48 cols, stride 65
#pragma unroll
  for (int ii = 0; ii < 4; ++ii)
#pragma unroll
    for (int c = 0; c < 3; ++c)
      lgt[(qi * 4 + ii) * 65 + ki * 3 + c] = lr[ii][c];
  __syncthreads();
  // ---- softmax: 4 threads per query row, 12 elems each ----
  {
    int r = t >> 2, c4 = t & 3;
    float vals[12];
    float m = -1e30f;
#pragma unroll
    for (int k = 0; k < 12; ++k) {
      vals[k] = lgt[r * 65 + c4 * 12 + k];
      m = fmaxf(m, vals[k]);
    }
    m = fmaxf(m, __shfl_xor(m, 1));
    m = fmaxf(m, __shfl_xor(m, 2));
    float s = 0.f;
#pragma unroll
    for (int k = 0; k < 12; ++k) {
      vals[k] = expf(vals[k] - m);
      s += vals[k];
    }
    s += __shfl_xor(s, 1);
    s += __shfl_xor(s, 2);
    float inv = 1.0f / s;
#pragma unroll
    for (int k = 0; k < 12; ++k) lgt[r * 65 + c4 * 12 + k] = vals[k] * inv;
  }
  __syncthreads();
  // ---- PV: thread = (qi2: 4 queries, di: 4 d's) ----
  int qi2 = t & 15, di = t >> 4;
  int g2 = qi2 >> 1;
  float acc[4][4] = {};
#pragma unroll 8
  for (int l = 0; l < 48; ++l) {
    float p[4];
#pragma unroll
    for (int ii = 0; ii < 4; ++ii) p[ii] = lgt[(qi2 * 4 + ii) * 65 + l];
    const float* vrow = (l < 32) ? (VcS + l * 65) : (VwS + (g2 * 8 + l - 32) * 65);
    float vv[4];
#pragma unroll
    for (int jj = 0; jj < 4; ++jj) vv[jj] = vrow[di * 4 + jj];
#pragma unroll
    for (int ii = 0; ii < 4; ++ii)
#pragma unroll
      for (int jj = 0; jj < 4; ++jj) acc[ii][jj] += p[ii] * vv[jj];
  }
#pragma unroll
  for (int ii = 0; ii < 4; ++ii) {
    int w = qi2 * 4 + ii;
    float4 o4 = make_float4(acc[ii][0], acc[ii][1], acc[ii][2], acc[ii][3]);
    *(float4*)(qc + ((size_t)(b * 4096 + s0 + w)) * 1024 + hoff + di * 4) = o4;
  }
}

// ---------------------------------------------------------------------------
extern "C" void kernel_launch(void* const* d_in, const int* in_sizes, int n_in,
                              void* d_out, int out_size, void* d_ws,
                              size_t ws_size, hipStream_t stream) {
  const float* query = (const float*)d_in[0];
  const float* Wq = (const float*)d_in[1];
  const float* bq = (const float*)d_in[2];
  const float* Wk = (const float*)d_in[3];
  const float* bk = (const float*)d_in[4];
  const float* Wv = (const float*)d_in[5];
  const float* bv = (const float*)d_in[6];
  const float* Wo = (const float*)d_in[7];
  const float* bo = (const float*)d_in[8];
  const float* g_l = (const float*)d_in[9];
  const float* b_l = (const float*)d_in[10];
  const float* g_s = (const float*)d_in[11];
  const float* b_s = (const float*)d_in[12];
  const float* Wd = (const float*)d_in[13];
  const float* bd = (const float*)d_in[14];
  float* out = (float*)d_out;

  float* ws = (float*)d_ws;
  float* q_buf = ws;                       // 16777216  (Q, then C in-place)
  float* k_buf = q_buf + 16777216;         // 16777216
  float* v_buf = k_buf + 16777216;         // 16777216
  float* yd_buf = v_buf + 16777216;        // 8388608
  float* stats = yd_buf + 8388608;         // 4096
  float* kc_part = stats + 4096;           // 1048576
  float* vc_part = kc_part + 1048576;      // 1048576
  float* kc_ln = vc_part + 1048576;        // 131072
  float* vc_ln = kc_ln + 131072;           // 131072

  dim3 blk(256);
  gemm_in<<<dim3(16, 256), blk, 0, stream>>>(query, Wq, bq, q_buf, 1024, 0.125f);
  gemm_in<<<dim3(16, 256), blk, 0, stream>>>(query, Wk, bk, k_buf, 1024, 1.0f);
  gemm_in<<<dim3(16, 256), blk, 0, stream>>>(query, Wv, bv, v_buf, 1024, 1.0f);
  gemm_in<<<dim3(8, 256), blk, 0, stream>>>(query, Wd, bd, yd_buf, 512, 1.0f);
  ln_rows<<<16384, blk, 0, stream>>>(k_buf, g_l, b_l);
  ln_rows<<<16384, blk, 0, stream>>>(v_buf, g_l, b_l);
  col_stats<<<dim3(8, 4), blk, 0, stream>>>(yd_buf, stats);
  compress<<<dim3(8, 16, 4), blk, 0, stream>>>(yd_buf, stats, k_buf, v_buf,
                                               kc_part, vc_part);
  ln_compress<<<128, blk, 0, stream>>>(kc_part, vc_part, g_s, b_s, kc_ln, vc_ln);
  attention<<<dim3(64, 16, 4), blk, 0, stream>>>(q_buf, k_buf, v_buf,
                                                 kc_ln, vc_ln);
  gemm_out<<<dim3(16, 256), blk, 0, stream>>>(q_buf, Wo, bo, out);
}

// Round 4
// 1249.609 us; speedup vs baseline: 3.0529x; 2.6073x over previous
//
#include <hip/hip_runtime.h>
#include <cstddef>
#include <cstdint>

// Problem constants
#define DIMC 1024
#define HC   16
#define DHC  64
#define LC   32
#define WC   8
#define EC   4
#define SEQC 4096
#define BC   4
#define MTOT 16384    // B * SEQ

typedef __attribute__((ext_vector_type(8))) __bf16 bf16x8;
typedef __attribute__((ext_vector_type(4))) float f32x4;

__device__ inline unsigned short f2b(float f) {
  unsigned int u = __float_as_uint(f);
  u += 0x7fff + ((u >> 16) & 1);   // round-to-nearest-even
  return (unsigned short)(u >> 16);
}
__device__ inline float b2f(unsigned short u) {
  return __uint_as_float(((unsigned int)u) << 16);
}

// async global->LDS, 16B/lane; LDS dest = wave-uniform base + lane*16.
// Proper generic->as(1)/as(3) addrspace casts (clang emits addrspacecast).
__device__ inline void gll16(const void* g, void* l) {
  __builtin_amdgcn_global_load_lds(
      (__attribute__((address_space(1))) void*)g,
      (__attribute__((address_space(3))) void*)l, 16, 0, 0);
}

// ---------------------------------------------------------------------------
// Row convert fp32 -> bf16 with (s,b,.)->(b,s,.) transpose folded in.
// grid 16384 x 256 thr, 4 elems/thread.
// ---------------------------------------------------------------------------
__global__ __launch_bounds__(256) void conv_rows(const float* __restrict__ src,
    unsigned short* __restrict__ dst) {
  int r = blockIdx.x;
  int sr = ((r & 4095) << 2) | (r >> 12);
  const float4* s = (const float4*)(src + (size_t)sr * 1024);
  ushort4* d = (ushort4*)(dst + (size_t)r * 1024);
  int t = threadIdx.x;
  float4 v = s[t];
  d[t] = make_ushort4(f2b(v.x), f2b(v.y), f2b(v.z), f2b(v.w));
}

// ---------------------------------------------------------------------------
// Weight convert + transpose: WT[n*1024 + k] = bf16(W[k*N + n]).
// grid (N/32, 32), block 256, 32x32 LDS tile (pad 33).
// ---------------------------------------------------------------------------
__global__ __launch_bounds__(256) void conv_wT(const float* __restrict__ W,
    unsigned short* __restrict__ WT, int N) {
  __shared__ float tile[32][33];
  int t = threadIdx.x;
  int tr = t >> 5, tc = t & 31;
  int n0 = blockIdx.x * 32, k0 = blockIdx.y * 32;
#pragma unroll
  for (int i = 0; i < 4; ++i)
    tile[tr + i * 8][tc] = W[(size_t)(k0 + tr + i * 8) * N + n0 + tc];
  __syncthreads();
#pragma unroll
  for (int i = 0; i < 4; ++i)
    WT[(size_t)(n0 + tr + i * 8) * 1024 + k0 + tc] = f2b(tile[tc][tr + i * 8]);
}

// ---------------------------------------------------------------------------
// bf16 MFMA GEMM (m97 structure): 128x128 tile, BK=32, 256 thr = 4 waves,
// each wave 64x64 (4x4 tiles of 16x16x32). A: M x 1024 bf16 row-major.
// BT: N x 1024 bf16 (B transposed, K-major fragments).
// mode 0: fp32 out. mode 1: fp32 out, row remap ((r&4095)<<2)|(r>>12).
// mode 2: bf16 out.
// ---------------------------------------------------------------------------
__global__ __launch_bounds__(256) void gemm_bf16(
    const unsigned short* __restrict__ A, const unsigned short* __restrict__ BT,
    const float* __restrict__ bias, void* __restrict__ outp,
    int N, float scale, int mode) {
  __shared__ unsigned short As[128 * 32];   // [row][k], 64B rows
  __shared__ unsigned short Bs[128 * 32];   // [n][k]
  int t = threadIdx.x;
  int w = t >> 6, lane = t & 63;
  int colBase = blockIdx.x * 128;
  int rowBase = blockIdx.y * 128;
  int wr = (w >> 1) * 64, wc = (w & 1) * 64;
  int srow = lane >> 2, sseg = (lane & 3) * 8;
  const unsigned short* Ag =
      A + (size_t)(rowBase + w * 32 + srow) * 1024 + sseg;
  const unsigned short* Bg =
      BT + (size_t)(colBase + w * 32 + srow) * 1024 + sseg;
  unsigned short* Al = As + (w * 32) * 32;  // wave-uniform LDS base
  unsigned short* Bl = Bs + (w * 32) * 32;
  int m = lane & 15, quad = lane >> 4;
  f32x4 acc[4][4] = {};
  for (int k0 = 0; k0 < 1024; k0 += 32) {
    gll16(Ag + k0, Al);
    gll16(Ag + (size_t)16 * 1024 + k0, Al + 16 * 32);
    gll16(Bg + k0, Bl);
    gll16(Bg + (size_t)16 * 1024 + k0, Bl + 16 * 32);
    __syncthreads();
    bf16x8 af[4], bfr[4];
#pragma unroll
    for (int i = 0; i < 4; ++i)
      af[i] = *(const bf16x8*)(As + (wr + i * 16 + m) * 32 + quad * 8);
#pragma unroll
    for (int j = 0; j < 4; ++j)
      bfr[j] = *(const bf16x8*)(Bs + (wc + j * 16 + m) * 32 + quad * 8);
#pragma unroll
    for (int i = 0; i < 4; ++i)
#pragma unroll
      for (int j = 0; j < 4; ++j)
        acc[i][j] = __builtin_amdgcn_mfma_f32_16x16x32_bf16(af[i], bfr[j],
                                                            acc[i][j], 0, 0, 0);
    __syncthreads();
  }
#pragma unroll
  for (int i = 0; i < 4; ++i) {
#pragma unroll
    for (int j = 0; j < 4; ++j) {
      int col = colBase + wc + j * 16 + m;
      float bv = bias[col];
#pragma unroll
      for (int r = 0; r < 4; ++r) {
        int rr = rowBase + wr + i * 16 + quad * 4 + r;
        float val = (acc[i][j][r] + bv) * scale;
        if (mode == 2) {
          ((unsigned short*)outp)[(size_t)rr * N + col] = f2b(val);
        } else {
          size_t orow = (mode == 1) ? (size_t)(((rr & 4095) << 2) | (rr >> 12))
                                    : (size_t)rr;
          ((float*)outp)[orow * N + col] = val;
        }
      }
    }
  }
}

// ---------------------------------------------------------------------------
// In-place row LayerNorm on bf16 buffer (1024 cols, fp32 math).
// ---------------------------------------------------------------------------
__global__ __launch_bounds__(256) void ln_bf(unsigned short* __restrict__ buf,
    const float* __restrict__ g, const float* __restrict__ b) {
  int row = blockIdx.x;
  unsigned short* p = buf + (size_t)row * 1024;
  int tid = threadIdx.x;
  ushort4 u4 = ((const ushort4*)p)[tid];
  float x0 = b2f(u4.x), x1 = b2f(u4.y), x2 = b2f(u4.z), x3 = b2f(u4.w);
  float s = x0 + x1 + x2 + x3;
  float ss = x0 * x0 + x1 * x1 + x2 * x2 + x3 * x3;
#pragma unroll
  for (int off = 32; off > 0; off >>= 1) {
    s += __shfl_down(s, off);
    ss += __shfl_down(ss, off);
  }
  __shared__ float sred[8], ssred[8];
  int wave = tid >> 6, lane = tid & 63;
  if (lane == 0) { sred[wave] = s; ssred[wave] = ss; }
  __syncthreads();
  if (tid == 0) {
    float S = 0, SS = 0;
    for (int w = 0; w < 4; ++w) { S += sred[w]; SS += ssred[w]; }
    float m = S * (1.0f / 1024.0f);
    float v = SS * (1.0f / 1024.0f) - m * m;
    sred[0] = m;
    ssred[0] = rsqrtf(v + 1e-5f);
  }
  __syncthreads();
  float m = sred[0], rinv = ssred[0];
  float4 gg = ((const float4*)g)[tid];
  float4 bb = ((const float4*)b)[tid];
  ushort4 y;
  y.x = f2b((x0 - m) * rinv * gg.x + bb.x);
  y.y = f2b((x1 - m) * rinv * gg.y + bb.y);
  y.z = f2b((x2 - m) * rinv * gg.z + bb.z);
  y.w = f2b((x3 - m) * rinv * gg.w + bb.w);
  ((ushort4*)p)[tid] = y;
}

// ---------------------------------------------------------------------------
// Column softmax stats (online, coalesced). grid (8, 4b), block 256.
// ---------------------------------------------------------------------------
__global__ __launch_bounds__(256) void col_stats(const float* __restrict__ yd,
    float* __restrict__ stats) {
  int cg = blockIdx.x, b = blockIdx.y;
  int t = threadIdx.x;
  int lane = t & 63, grp = t >> 6;
  const float* base = yd + (size_t)b * 4096 * 512 + cg * 64 + lane;
  float m = -1e30f, s = 0.f;
  for (int r = grp; r < 4096; r += 4) {
    float x = base[(size_t)r * 512];
    float mn = fmaxf(m, x);
    s = s * expf(m - mn) + expf(x - mn);
    m = mn;
  }
  __shared__ float mS[4][64], sS[4][64];
  mS[grp][lane] = m;
  sS[grp][lane] = s;
  __syncthreads();
  if (grp == 0) {
    float M = mS[0][lane], S = sS[0][lane];
#pragma unroll
    for (int k = 1; k < 4; ++k) {
      float m2 = mS[k][lane], s2 = sS[k][lane];
      float Mn = fmaxf(M, m2);
      S = S * expf(M - Mn) + s2 * expf(m2 - Mn);
      M = Mn;
    }
    int col = cg * 64 + lane;
    stats[((size_t)(b * 512 + col)) * 2] = M;
    stats[((size_t)(b * 512 + col)) * 2 + 1] = 1.0f / S;
  }
}

// ---------------------------------------------------------------------------
// Landmark compression partials; K/V now bf16.
// ---------------------------------------------------------------------------
#define SCHUNK 512
__global__ __launch_bounds__(256) void compress(const float* __restrict__ yd,
    const float* __restrict__ stats, const unsigned short* __restrict__ kbuf,
    const unsigned short* __restrict__ vbuf, float* __restrict__ kcp,
    float* __restrict__ vcp) {
  int c = blockIdx.x, h = blockIdx.y, b = blockIdx.z;
  int tid = threadIdx.x;
  int d = tid & 63, lgp = tid >> 6;
  __shared__ float mxS[32], isS[32];
  __shared__ float pS[16][33];
  if (tid < 32) {
    mxS[tid] = stats[(size_t)(b * 512 + h * 32 + tid) * 2];
    isS[tid] = stats[(size_t)(b * 512 + h * 32 + tid) * 2 + 1];
  }
  __syncthreads();
  float accK[8] = {};
  float accV[8] = {};
  int s0 = c * SCHUNK;
  for (int sc = 0; sc < SCHUNK; sc += 16) {
#pragma unroll
    for (int l2 = 0; l2 < 2; ++l2) {
      int idx = l2 * 256 + tid;
      int sl = idx >> 5, l = idx & 31;
      float v = yd[((size_t)(b * 4096 + s0 + sc + sl)) * 512 + h * 32 + l];
      pS[sl][l] = expf(v - mxS[l]) * isS[l];
    }
    __syncthreads();
#pragma unroll 4
    for (int sl = 0; sl < 16; ++sl) {
      size_t roff = ((size_t)(b * 4096 + s0 + sc + sl)) * 1024 + h * 64 + d;
      float kv = b2f(kbuf[roff]);
      float vv = b2f(vbuf[roff]);
#pragma unroll
      for (int j = 0; j < 8; ++j) {
        float p = pS[sl][lgp * 8 + j];
        accK[j] += p * kv;
        accV[j] += p * vv;
      }
    }
    __syncthreads();
  }
#pragma unroll
  for (int j = 0; j < 8; ++j) {
    int l = lgp * 8 + j;
    size_t o = ((((size_t)c * 4 + b) * 16 + h) * 32 + l) * 64 + d;
    kcp[o] = accK[j];
    vcp[o] = accV[j];
  }
}

// ---------------------------------------------------------------------------
// Reduce compression partials + LayerNorm (fp32 throughout).
// ---------------------------------------------------------------------------
__global__ __launch_bounds__(256) void ln_compress(const float* __restrict__ kcp,
    const float* __restrict__ vcp, const float* __restrict__ g_s,
    const float* __restrict__ b_s, float* __restrict__ kc_ln,
    float* __restrict__ vc_ln) {
  int row = blockIdx.x;
  int b = row >> 5, l = row & 31;
  int tid = threadIdx.x;
  __shared__ float xs[1024];
  __shared__ float red[8], red2[8];
  for (int t = 0; t < 2; ++t) {
    const float* part = t ? vcp : kcp;
    float* outp = t ? vc_ln : kc_ln;
    float lsum = 0, lss = 0;
#pragma unroll
    for (int q = 0; q < 4; ++q) {
      int j = q * 256 + tid;
      int h = j >> 6, d = j & 63;
      float x = 0;
      for (int cch = 0; cch < 8; ++cch)
        x += part[((((size_t)cch * 4 + b) * 16 + h) * 32 + l) * 64 + d];
      xs[j] = x;
      lsum += x;
      lss += x * x;
    }
#pragma unroll
    for (int off = 32; off > 0; off >>= 1) {
      lsum += __shfl_down(lsum, off);
      lss += __shfl_down(lss, off);
    }
    int wave = tid >> 6, lane = tid & 63;
    if (lane == 0) { red[wave] = lsum; red2[wave] = lss; }
    __syncthreads();
    if (tid == 0) {
      float S = 0, SS = 0;
      for (int w = 0; w < 4; ++w) { S += red[w]; SS += red2[w]; }
      float m = S * (1.0f / 1024.0f);
      float v = SS * (1.0f / 1024.0f) - m * m;
      red[0] = m;
      red2[0] = rsqrtf(v + 1e-5f);
    }
    __syncthreads();
    float m = red[0], rinv = red2[0];
#pragma unroll
    for (int q = 0; q < 4; ++q) {
      int j = q * 256 + tid;
      outp[(size_t)row * 1024 + j] = (xs[j] - m) * rinv * g_s[j] + b_s[j];
    }
    __syncthreads();
  }
}

// ---------------------------------------------------------------------------
// Fused attention: 256 thr, 64 queries per block, 65-stride LDS tiles.
// Q/K/V in bf16; Kc/Vc fp32; C written bf16 in place over Q.
// ---------------------------------------------------------------------------
__global__ __launch_bounds__(256) void attention(unsigned short* __restrict__ qc,
    const unsigned short* __restrict__ kbuf,
    const unsigned short* __restrict__ vbuf,
    const float* __restrict__ kc_ln, const float* __restrict__ vc_ln) {
  int qt = blockIdx.x, h = blockIdx.y, b = blockIdx.z;
  int t = threadIdx.x;
  __shared__ float smem[272 * 65];
  float* KcS = smem;               // 32 x 65
  float* VcS = KcS + 32 * 65;      // 32 x 65
  float* KwS = VcS + 32 * 65;      // 72 x 65
  float* VwS = KwS + 72 * 65;      // 72 x 65
  float* qS  = VwS + 72 * 65;      // 64 x 65 (later: logits)
  int s0 = qt * 64;
  int hoff = h * 64;
#pragma unroll
  for (int it = 0; it < 8; ++it) {
    int idx = it * 256 + t;
    int l = idx >> 6, d = idx & 63;
    size_t o = ((size_t)(b * 32 + l)) * 1024 + hoff + d;
    KcS[l * 65 + d] = kc_ln[o];
    VcS[l * 65 + d] = vc_ln[o];
  }
#pragma unroll
  for (int it = 0; it < 16; ++it) {
    int idx = it * 256 + t;
    int w = idx >> 6, d = idx & 63;
    qS[w * 65 + d] = b2f(qc[((size_t)(b * 4096 + s0 + w)) * 1024 + hoff + d]);
  }
#pragma unroll
  for (int it = 0; it < 18; ++it) {
    int idx = it * 256 + t;
    int r = idx >> 6, d = idx & 63;
    int pos = s0 - 4 + r;
    bool ok = (pos >= 0) && (pos < 4096);
    size_t o = ((size_t)(b * 4096 + pos)) * 1024 + hoff + d;
    KwS[r * 65 + d] = ok ? b2f(kbuf[o]) : 0.f;
    VwS[r * 65 + d] = ok ? b2f(vbuf[o]) : 0.f;
  }
  __syncthreads();
  int qi = t & 15, ki = t >> 4;
  int g = qi >> 1;
  float lr[4][3] = {};
#pragma unroll 8
  for (int j = 0; j < 64; ++j) {
    float a[4];
#pragma unroll
    for (int ii = 0; ii < 4; ++ii) a[ii] = qS[(qi * 4 + ii) * 65 + j];
    float bb[3];
#pragma unroll
    for (int c = 0; c < 3; ++c) {
      int kk = ki * 3 + c;
      bb[c] = (kk < 32) ? KcS[kk * 65 + j] : KwS[(g * 8 + kk - 32) * 65 + j];
    }
#pragma unroll
    for (int ii = 0; ii < 4; ++ii)
#pragma unroll
      for (int c = 0; c < 3; ++c) lr[ii][c] += a[ii] * bb[c];
  }
#pragma unroll
  for (int c = 0; c < 3; ++c) {
    int kk = ki * 3 + c;
    if (kk >= 32) {
      int pos = s0 + g * 8 - 4 + (kk - 32);
      if (pos < 0 || pos >= 4096) {
#pragma unroll
        for (int ii = 0; ii < 4; ++ii) lr[ii][c] = -INFINITY;
      }
    }
  }
  __syncthreads();
  float* lgt = qS;
#pragma unroll
  for (int ii = 0; ii < 4; ++ii)
#pragma unroll
    for (int c = 0; c < 3; ++c)
      lgt[(qi * 4 + ii) * 65 + ki * 3 + c] = lr[ii][c];
  __syncthreads();
  {
    int r = t >> 2, c4 = t & 3;
    float vals[12];
    float m = -1e30f;
#pragma unroll
    for (int k = 0; k < 12; ++k) {
      vals[k] = lgt[r * 65 + c4 * 12 + k];
      m = fmaxf(m, vals[k]);
    }
    m = fmaxf(m, __shfl_xor(m, 1));
    m = fmaxf(m, __shfl_xor(m, 2));
    float s = 0.f;
#pragma unroll
    for (int k = 0; k < 12; ++k) {
      vals[k] = expf(vals[k] - m);
      s += vals[k];
    }
    s += __shfl_xor(s, 1);
    s += __shfl_xor(s, 2);
    float inv = 1.0f / s;
#pragma unroll
    for (int k = 0; k < 12; ++k) lgt[r * 65 + c4 * 12 + k] = vals[k] * inv;
  }
  __syncthreads();
  int qi2 = t & 15, di = t >> 4;
  int g2 = qi2 >> 1;
  float acc[4][4] = {};
#pragma unroll 8
  for (int l = 0; l < 48; ++l) {
    float p[4];
#pragma unroll
    for (int ii = 0; ii < 4; ++ii) p[ii] = lgt[(qi2 * 4 + ii) * 65 + l];
    const float* vrow = (l < 32) ? (VcS + l * 65) : (VwS + (g2 * 8 + l - 32) * 65);
    float vv[4];
#pragma unroll
    for (int jj = 0; jj < 4; ++jj) vv[jj] = vrow[di * 4 + jj];
#pragma unroll
    for (int ii = 0; ii < 4; ++ii)
#pragma unroll
      for (int jj = 0; jj < 4; ++jj) acc[ii][jj] += p[ii] * vv[jj];
  }
#pragma unroll
  for (int ii = 0; ii < 4; ++ii) {
    int w = qi2 * 4 + ii;
    ushort4 o4 = make_ushort4(f2b(acc[ii][0]), f2b(acc[ii][1]),
                              f2b(acc[ii][2]), f2b(acc[ii][3]));
    *(ushort4*)(qc + ((size_t)(b * 4096 + s0 + w)) * 1024 + hoff + di * 4) = o4;
  }
}

// ---------------------------------------------------------------------------
extern "C" void kernel_launch(void* const* d_in, const int* in_sizes, int n_in,
                              void* d_out, int out_size, void* d_ws,
                              size_t ws_size, hipStream_t stream) {
  const float* query = (const float*)d_in[0];
  const float* Wq = (const float*)d_in[1];
  const float* bq = (const float*)d_in[2];
  const float* Wk = (const float*)d_in[3];
  const float* bk = (const float*)d_in[4];
  const float* Wv = (const float*)d_in[5];
  const float* bv = (const float*)d_in[6];
  const float* Wo = (const float*)d_in[7];
  const float* bo = (const float*)d_in[8];
  const float* g_l = (const float*)d_in[9];
  const float* b_l = (const float*)d_in[10];
  const float* g_s = (const float*)d_in[11];
  const float* b_s = (const float*)d_in[12];
  const float* Wd = (const float*)d_in[13];
  const float* bd = (const float*)d_in[14];
  float* out = (float*)d_out;

  // Workspace layout, 186.7 MB total (proven bound from R0-R2: >= 244.7 MB ok)
  unsigned short* qb = (unsigned short*)d_ws;  // 16,777,216 bf16 (Q, then C)
  unsigned short* kb = qb + 16777216;          // 16,777,216 bf16
  unsigned short* vb = kb + 16777216;          // 16,777,216 bf16
  unsigned short* xb = vb + 16777216;          // 16,777,216 bf16 (X)
  float* yd = (float*)(xb + 16777216);         // 8,388,608 fp32
  float* stats = yd + 8388608;                 // 4,096
  float* kc_part = stats + 4096;               // 1,048,576
  float* vc_part = kc_part + 1048576;          // 1,048,576
  float* kc_ln = vc_part + 1048576;            // 131,072
  float* vc_ln = kc_ln + 131072;               // 131,072
  unsigned short* wqT = (unsigned short*)(vc_ln + 131072);  // 1,048,576 each
  unsigned short* wkT = wqT + 1048576;
  unsigned short* wvT = wkT + 1048576;
  unsigned short* woT = wvT + 1048576;
  unsigned short* wdT = woT + 1048576;         // 524,288

  dim3 blk(256);
  // bf16 conversions
  conv_rows<<<16384, blk, 0, stream>>>(query, xb);
  conv_wT<<<dim3(32, 32), blk, 0, stream>>>(Wq, wqT, 1024);
  conv_wT<<<dim3(32, 32), blk, 0, stream>>>(Wk, wkT, 1024);
  conv_wT<<<dim3(32, 32), blk, 0, stream>>>(Wv, wvT, 1024);
  conv_wT<<<dim3(32, 32), blk, 0, stream>>>(Wo, woT, 1024);
  conv_wT<<<dim3(16, 32), blk, 0, stream>>>(Wd, wdT, 512);
  // MFMA projections (Q/K/V -> bf16 out, head-scores -> fp32 out)
  gemm_bf16<<<dim3(8, 128), blk, 0, stream>>>(xb, wqT, bq, qb, 1024, 0.125f, 2);
  gemm_bf16<<<dim3(8, 128), blk, 0, stream>>>(xb, wkT, bk, kb, 1024, 1.0f, 2);
  gemm_bf16<<<dim3(8, 128), blk, 0, stream>>>(xb, wvT, bv, vb, 1024, 1.0f, 2);
  gemm_bf16<<<dim3(4, 128), blk, 0, stream>>>(xb, wdT, bd, yd, 512, 1.0f, 0);
  // LN K, V (in-place bf16)
  ln_bf<<<16384, blk, 0, stream>>>(kb, g_l, b_l);
  ln_bf<<<16384, blk, 0, stream>>>(vb, g_l, b_l);
  // head-score softmax stats + landmark compression + LN
  col_stats<<<dim3(8, 4), blk, 0, stream>>>(yd, stats);
  compress<<<dim3(8, 16, 4), blk, 0, stream>>>(yd, stats, kb, vb,
                                               kc_part, vc_part);
  ln_compress<<<128, blk, 0, stream>>>(kc_part, vc_part, g_s, b_s, kc_ln, vc_ln);
  // fused attention (bf16 C overwrites qb)
  attention<<<dim3(64, 16, 4), blk, 0, stream>>>(qb, kb, vb, kc_ln, vc_ln);
  // output projection (+ (b,s)->(s,b) remap), reads bf16 C directly
  gemm_bf16<<<dim3(8, 128), blk, 0, stream>>>(qb, woT, bo, out, 1024, 1.0f, 1);
}

// Round 5
// 953.317 us; speedup vs baseline: 4.0017x; 1.3108x over previous
//
#include <hip/hip_runtime.h>
#include <cstddef>
#include <cstdint>

// Problem constants
#define DIMC 1024
#define HC   16
#define DHC  64
#define LC   32
#define WC   8
#define EC   4
#define SEQC 4096
#define BC   4
#define MTOT 16384    // B * SEQ

typedef __attribute__((ext_vector_type(8))) __bf16 bf16x8;
typedef __attribute__((ext_vector_type(4))) float f32x4;

__device__ inline unsigned short f2b(float f) {
  unsigned int u = __float_as_uint(f);
  u += 0x7fff + ((u >> 16) & 1);   // round-to-nearest-even
  return (unsigned short)(u >> 16);
}
__device__ inline float b2f(unsigned short u) {
  return __uint_as_float(((unsigned int)u) << 16);
}

// async global->LDS, 16B/lane; LDS dest = wave-uniform base + lane*16.
__device__ inline void gll16(const void* g, void* l) {
  __builtin_amdgcn_global_load_lds(
      (__attribute__((address_space(1))) void*)g,
      (__attribute__((address_space(3))) void*)l, 16, 0, 0);
}

// ---------------------------------------------------------------------------
// Row convert fp32 -> bf16 with (s,b,.)->(b,s,.) transpose folded in.
// ---------------------------------------------------------------------------
__global__ __launch_bounds__(256) void conv_rows(const float* __restrict__ src,
    unsigned short* __restrict__ dst) {
  int r = blockIdx.x;
  int sr = ((r & 4095) << 2) | (r >> 12);
  const float4* s = (const float4*)(src + (size_t)sr * 1024);
  ushort4* d = (ushort4*)(dst + (size_t)r * 1024);
  int t = threadIdx.x;
  float4 v = s[t];
  d[t] = make_ushort4(f2b(v.x), f2b(v.y), f2b(v.z), f2b(v.w));
}

// ---------------------------------------------------------------------------
// Weight convert + transpose: WT[n*1024 + k] = bf16(W[k*N + n]).
// ---------------------------------------------------------------------------
__global__ __launch_bounds__(256) void conv_wT(const float* __restrict__ W,
    unsigned short* __restrict__ WT, int N) {
  __shared__ float tile[32][33];
  int t = threadIdx.x;
  int tr = t >> 5, tc = t & 31;
  int n0 = blockIdx.x * 32, k0 = blockIdx.y * 32;
#pragma unroll
  for (int i = 0; i < 4; ++i)
    tile[tr + i * 8][tc] = W[(size_t)(k0 + tr + i * 8) * N + n0 + tc];
  __syncthreads();
#pragma unroll
  for (int i = 0; i < 4; ++i)
    WT[(size_t)(n0 + tr + i * 8) * 1024 + k0 + tc] = f2b(tile[tc][tr + i * 8]);
}

// ---------------------------------------------------------------------------
// bf16 MFMA GEMM (m97 structure): 128x128 tile, BK=32, 256 thr = 4 waves.
// mode 0: fp32 out. mode 1: fp32 out, row remap. mode 2: bf16 out.
// ---------------------------------------------------------------------------
__global__ __launch_bounds__(256) void gemm_bf16(
    const unsigned short* __restrict__ A, const unsigned short* __restrict__ BT,
    const float* __restrict__ bias, void* __restrict__ outp,
    int N, float scale, int mode) {
  __shared__ unsigned short As[128 * 32];   // [row][k], 64B rows
  __shared__ unsigned short Bs[128 * 32];   // [n][k]
  int t = threadIdx.x;
  int w = t >> 6, lane = t & 63;
  int colBase = blockIdx.x * 128;
  int rowBase = blockIdx.y * 128;
  int wr = (w >> 1) * 64, wc = (w & 1) * 64;
  int srow = lane >> 2, sseg = (lane & 3) * 8;
  const unsigned short* Ag =
      A + (size_t)(rowBase + w * 32 + srow) * 1024 + sseg;
  const unsigned short* Bg =
      BT + (size_t)(colBase + w * 32 + srow) * 1024 + sseg;
  unsigned short* Al = As + (w * 32) * 32;  // wave-uniform LDS base
  unsigned short* Bl = Bs + (w * 32) * 32;
  int m = lane & 15, quad = lane >> 4;
  f32x4 acc[4][4] = {};
  for (int k0 = 0; k0 < 1024; k0 += 32) {
    gll16(Ag + k0, Al);
    gll16(Ag + (size_t)16 * 1024 + k0, Al + 16 * 32);
    gll16(Bg + k0, Bl);
    gll16(Bg + (size_t)16 * 1024 + k0, Bl + 16 * 32);
    __syncthreads();
    bf16x8 af[4], bfr[4];
#pragma unroll
    for (int i = 0; i < 4; ++i)
      af[i] = *(const bf16x8*)(As + (wr + i * 16 + m) * 32 + quad * 8);
#pragma unroll
    for (int j = 0; j < 4; ++j)
      bfr[j] = *(const bf16x8*)(Bs + (wc + j * 16 + m) * 32 + quad * 8);
#pragma unroll
    for (int i = 0; i < 4; ++i)
#pragma unroll
      for (int j = 0; j < 4; ++j)
        acc[i][j] = __builtin_amdgcn_mfma_f32_16x16x32_bf16(af[i], bfr[j],
                                                            acc[i][j], 0, 0, 0);
    __syncthreads();
  }
#pragma unroll
  for (int i = 0; i < 4; ++i) {
#pragma unroll
    for (int j = 0; j < 4; ++j) {
      int col = colBase + wc + j * 16 + m;
      float bv = bias[col];
#pragma unroll
      for (int r = 0; r < 4; ++r) {
        int rr = rowBase + wr + i * 16 + quad * 4 + r;
        float val = (acc[i][j][r] + bv) * scale;
        if (mode == 2) {
          ((unsigned short*)outp)[(size_t)rr * N + col] = f2b(val);
        } else {
          size_t orow = (mode == 1) ? (size_t)(((rr & 4095) << 2) | (rr >> 12))
                                    : (size_t)rr;
          ((float*)outp)[orow * N + col] = val;
        }
      }
    }
  }
}

// ---------------------------------------------------------------------------
// In-place row LayerNorm on bf16 buffer (1024 cols, fp32 math).
// ---------------------------------------------------------------------------
__global__ __launch_bounds__(256) void ln_bf(unsigned short* __restrict__ buf,
    const float* __restrict__ g, const float* __restrict__ b) {
  int row = blockIdx.x;
  unsigned short* p = buf + (size_t)row * 1024;
  int tid = threadIdx.x;
  ushort4 u4 = ((const ushort4*)p)[tid];
  float x0 = b2f(u4.x), x1 = b2f(u4.y), x2 = b2f(u4.z), x3 = b2f(u4.w);
  float s = x0 + x1 + x2 + x3;
  float ss = x0 * x0 + x1 * x1 + x2 * x2 + x3 * x3;
#pragma unroll
  for (int off = 32; off > 0; off >>= 1) {
    s += __shfl_down(s, off);
    ss += __shfl_down(ss, off);
  }
  __shared__ float sred[8], ssred[8];
  int wave = tid >> 6, lane = tid & 63;
  if (lane == 0) { sred[wave] = s; ssred[wave] = ss; }
  __syncthreads();
  if (tid == 0) {
    float S = 0, SS = 0;
    for (int w = 0; w < 4; ++w) { S += sred[w]; SS += ssred[w]; }
    float m = S * (1.0f / 1024.0f);
    float v = SS * (1.0f / 1024.0f) - m * m;
    sred[0] = m;
    ssred[0] = rsqrtf(v + 1e-5f);
  }
  __syncthreads();
  float m = sred[0], rinv = ssred[0];
  float4 gg = ((const float4*)g)[tid];
  float4 bb = ((const float4*)b)[tid];
  ushort4 y;
  y.x = f2b((x0 - m) * rinv * gg.x + bb.x);
  y.y = f2b((x1 - m) * rinv * gg.y + bb.y);
  y.z = f2b((x2 - m) * rinv * gg.z + bb.z);
  y.w = f2b((x3 - m) * rinv * gg.w + bb.w);
  ((ushort4*)p)[tid] = y;
}

// ---------------------------------------------------------------------------
// Column softmax stats, phase A: per-chunk partials.
// grid (8 colgroups, 4 b, 16 schunks), block 256 (4 rowgrp x 64 lanes).
// Partials: pm/ps[(b*512+col)*16 + sc]
// ---------------------------------------------------------------------------
__global__ __launch_bounds__(256) void col_part(const float* __restrict__ yd,
    float* __restrict__ pm, float* __restrict__ ps) {
  int cg = blockIdx.x, b = blockIdx.y, sc = blockIdx.z;
  int t = threadIdx.x;
  int lane = t & 63, grp = t >> 6;
  const float* base = yd + (size_t)b * 4096 * 512 + (size_t)(sc * 256) * 512 +
                      cg * 64 + lane;
  float m = -1e30f, s = 0.f;
  for (int r = grp; r < 256; r += 4) {
    float x = base[(size_t)r * 512];
    float mn = fmaxf(m, x);
    s = s * expf(m - mn) + expf(x - mn);
    m = mn;
  }
  __shared__ float mS[4][64], sS[4][64];
  mS[grp][lane] = m;
  sS[grp][lane] = s;
  __syncthreads();
  if (grp == 0) {
    float M = mS[0][lane], S = sS[0][lane];
#pragma unroll
    for (int k = 1; k < 4; ++k) {
      float m2 = mS[k][lane], s2 = sS[k][lane];
      float Mn = fmaxf(M, m2);
      S = S * expf(M - Mn) + s2 * expf(m2 - Mn);
      M = Mn;
    }
    int col = cg * 64 + lane;
    pm[((size_t)(b * 512 + col)) * 16 + sc] = M;
    ps[((size_t)(b * 512 + col)) * 16 + sc] = S;
  }
}

// ---------------------------------------------------------------------------
// Column softmax stats, phase B: merge 16 partials per column.
// grid 8 x 256 threads = 2048 columns.
// ---------------------------------------------------------------------------
__global__ __launch_bounds__(256) void col_combine(const float* __restrict__ pm,
    const float* __restrict__ ps, float* __restrict__ stats) {
  int idx = blockIdx.x * 256 + threadIdx.x;  // (b*512+col)
  float M = -1e30f, S = 0.f;
#pragma unroll
  for (int sc = 0; sc < 16; ++sc) {
    float m2 = pm[(size_t)idx * 16 + sc], s2 = ps[(size_t)idx * 16 + sc];
    float Mn = fmaxf(M, m2);
    S = S * expf(M - Mn) + s2 * expf(m2 - Mn);
    M = Mn;
  }
  stats[(size_t)idx * 2] = M;
  stats[(size_t)idx * 2 + 1] = 1.0f / S;
}

// ---------------------------------------------------------------------------
// Landmark compression partials; K/V bf16.
// ---------------------------------------------------------------------------
#define SCHUNK 512
__global__ __launch_bounds__(256) void compress(const float* __restrict__ yd,
    const float* __restrict__ stats, const unsigned short* __restrict__ kbuf,
    const unsigned short* __restrict__ vbuf, float* __restrict__ kcp,
    float* __restrict__ vcp) {
  int c = blockIdx.x, h = blockIdx.y, b = blockIdx.z;
  int tid = threadIdx.x;
  int d = tid & 63, lgp = tid >> 6;
  __shared__ float mxS[32], isS[32];
  __shared__ float pS[16][33];
  if (tid < 32) {
    mxS[tid] = stats[(size_t)(b * 512 + h * 32 + tid) * 2];
    isS[tid] = stats[(size_t)(b * 512 + h * 32 + tid) * 2 + 1];
  }
  __syncthreads();
  float accK[8] = {};
  float accV[8] = {};
  int s0 = c * SCHUNK;
  for (int sc = 0; sc < SCHUNK; sc += 16) {
#pragma unroll
    for (int l2 = 0; l2 < 2; ++l2) {
      int idx = l2 * 256 + tid;
      int sl = idx >> 5, l = idx & 31;
      float v = yd[((size_t)(b * 4096 + s0 + sc + sl)) * 512 + h * 32 + l];
      pS[sl][l] = expf(v - mxS[l]) * isS[l];
    }
    __syncthreads();
#pragma unroll 4
    for (int sl = 0; sl < 16; ++sl) {
      size_t roff = ((size_t)(b * 4096 + s0 + sc + sl)) * 1024 + h * 64 + d;
      float kv = b2f(kbuf[roff]);
      float vv = b2f(vbuf[roff]);
#pragma unroll
      for (int j = 0; j < 8; ++j) {
        float p = pS[sl][lgp * 8 + j];
        accK[j] += p * kv;
        accV[j] += p * vv;
      }
    }
    __syncthreads();
  }
#pragma unroll
  for (int j = 0; j < 8; ++j) {
    int l = lgp * 8 + j;
    size_t o = ((((size_t)c * 4 + b) * 16 + h) * 32 + l) * 64 + d;
    kcp[o] = accK[j];
    vcp[o] = accV[j];
  }
}

// ---------------------------------------------------------------------------
// Reduce compression partials + LayerNorm (fp32).
// ---------------------------------------------------------------------------
__global__ __launch_bounds__(256) void ln_compress(const float* __restrict__ kcp,
    const float* __restrict__ vcp, const float* __restrict__ g_s,
    const float* __restrict__ b_s, float* __restrict__ kc_ln,
    float* __restrict__ vc_ln) {
  int row = blockIdx.x;
  int b = row >> 5, l = row & 31;
  int tid = threadIdx.x;
  __shared__ float xs[1024];
  __shared__ float red[8], red2[8];
  for (int t = 0; t < 2; ++t) {
    const float* part = t ? vcp : kcp;
    float* outp = t ? vc_ln : kc_ln;
    float lsum = 0, lss = 0;
#pragma unroll
    for (int q = 0; q < 4; ++q) {
      int j = q * 256 + tid;
      int h = j >> 6, d = j & 63;
      float x = 0;
      for (int cch = 0; cch < 8; ++cch)
        x += part[((((size_t)cch * 4 + b) * 16 + h) * 32 + l) * 64 + d];
      xs[j] = x;
      lsum += x;
      lss += x * x;
    }
#pragma unroll
    for (int off = 32; off > 0; off >>= 1) {
      lsum += __shfl_down(lsum, off);
      lss += __shfl_down(lss, off);
    }
    int wave = tid >> 6, lane = tid & 63;
    if (lane == 0) { red[wave] = lsum; red2[wave] = lss; }
    __syncthreads();
    if (tid == 0) {
      float S = 0, SS = 0;
      for (int w = 0; w < 4; ++w) { S += red[w]; SS += red2[w]; }
      float m = S * (1.0f / 1024.0f);
      float v = SS * (1.0f / 1024.0f) - m * m;
      red[0] = m;
      red2[0] = rsqrtf(v + 1e-5f);
    }
    __syncthreads();
    float m = red[0], rinv = red2[0];
#pragma unroll
    for (int q = 0; q < 4; ++q) {
      int j = q * 256 + tid;
      outp[(size_t)row * 1024 + j] = (xs[j] - m) * rinv * g_s[j] + b_s[j];
    }
    __syncthreads();
  }
}

// ---------------------------------------------------------------------------
// Fused attention: 256 thr, 64 queries per block, 65-stride LDS tiles.
// ---------------------------------------------------------------------------
__global__ __launch_bounds__(256) void attention(unsigned short* __restrict__ qc,
    const unsigned short* __restrict__ kbuf,
    const unsigned short* __restrict__ vbuf,
    const float* __restrict__ kc_ln, const float* __restrict__ vc_ln) {
  int qt = blockIdx.x, h = blockIdx.y, b = blockIdx.z;
  int t = threadIdx.x;
  __shared__ float smem[272 * 65];
  float* KcS = smem;               // 32 x 65
  float* VcS = KcS + 32 * 65;      // 32 x 65
  float* KwS = VcS + 32 * 65;      // 72 x 65
  float* VwS = KwS + 72 * 65;      // 72 x 65
  float* qS  = VwS + 72 * 65;      // 64 x 65 (later: logits)
  int s0 = qt * 64;
  int hoff = h * 64;
#pragma unroll
  for (int it = 0; it < 8; ++it) {
    int idx = it * 256 + t;
    int l = idx >> 6, d = idx & 63;
    size_t o = ((size_t)(b * 32 + l)) * 1024 + hoff + d;
    KcS[l * 65 + d] = kc_ln[o];
    VcS[l * 65 + d] = vc_ln[o];
  }
#pragma unroll
  for (int it = 0; it < 16; ++it) {
    int idx = it * 256 + t;
    int w = idx >> 6, d = idx & 63;
    qS[w * 65 + d] = b2f(qc[((size_t)(b * 4096 + s0 + w)) * 1024 + hoff + d]);
  }
#pragma unroll
  for (int it = 0; it < 18; ++it) {
    int idx = it * 256 + t;
    int r = idx >> 6, d = idx & 63;
    int pos = s0 - 4 + r;
    bool ok = (pos >= 0) && (pos < 4096);
    size_t o = ((size_t)(b * 4096 + pos)) * 1024 + hoff + d;
    KwS[r * 65 + d] = ok ? b2f(kbuf[o]) : 0.f;
    VwS[r * 65 + d] = ok ? b2f(vbuf[o]) : 0.f;
  }
  __syncthreads();
  int qi = t & 15, ki = t >> 4;
  int g = qi >> 1;
  float lr[4][3] = {};
#pragma unroll 8
  for (int j = 0; j < 64; ++j) {
    float a[4];
#pragma unroll
    for (int ii = 0; ii < 4; ++ii) a[ii] = qS[(qi * 4 + ii) * 65 + j];
    float bb[3];
#pragma unroll
    for (int c = 0; c < 3; ++c) {
      int kk = ki * 3 + c;
      bb[c] = (kk < 32) ? KcS[kk * 65 + j] : KwS[(g * 8 + kk - 32) * 65 + j];
    }
#pragma unroll
    for (int ii = 0; ii < 4; ++ii)
#pragma unroll
      for (int c = 0; c < 3; ++c) lr[ii][c] += a[ii] * bb[c];
  }
#pragma unroll
  for (int c = 0; c < 3; ++c) {
    int kk = ki * 3 + c;
    if (kk >= 32) {
      int pos = s0 + g * 8 - 4 + (kk - 32);
      if (pos < 0 || pos >= 4096) {
#pragma unroll
        for (int ii = 0; ii < 4; ++ii) lr[ii][c] = -INFINITY;
      }
    }
  }
  __syncthreads();
  float* lgt = qS;
#pragma unroll
  for (int ii = 0; ii < 4; ++ii)
#pragma unroll
    for (int c = 0; c < 3; ++c)
      lgt[(qi * 4 + ii) * 65 + ki * 3 + c] = lr[ii][c];
  __syncthreads();
  {
    int r = t >> 2, c4 = t & 3;
    float vals[12];
    float m = -1e30f;
#pragma unroll
    for (int k = 0; k < 12; ++k) {
      vals[k] = lgt[r * 65 + c4 * 12 + k];
      m = fmaxf(m, vals[k]);
    }
    m = fmaxf(m, __shfl_xor(m, 1));
    m = fmaxf(m, __shfl_xor(m, 2));
    float s = 0.f;
#pragma unroll
    for (int k = 0; k < 12; ++k) {
      vals[k] = expf(vals[k] - m);
      s += vals[k];
    }
    s += __shfl_xor(s, 1);
    s += __shfl_xor(s, 2);
    float inv = 1.0f / s;
#pragma unroll
    for (int k = 0; k < 12; ++k) lgt[r * 65 + c4 * 12 + k] = vals[k] * inv;
  }
  __syncthreads();
  int qi2 = t & 15, di = t >> 4;
  int g2 = qi2 >> 1;
  float acc[4][4] = {};
#pragma unroll 8
  for (int l = 0; l < 48; ++l) {
    float p[4];
#pragma unroll
    for (int ii = 0; ii < 4; ++ii) p[ii] = lgt[(qi2 * 4 + ii) * 65 + l];
    const float* vrow = (l < 32) ? (VcS + l * 65) : (VwS + (g2 * 8 + l - 32) * 65);
    float vv[4];
#pragma unroll
    for (int jj = 0; jj < 4; ++jj) vv[jj] = vrow[di * 4 + jj];
#pragma unroll
    for (int ii = 0; ii < 4; ++ii)
#pragma unroll
      for (int jj = 0; jj < 4; ++jj) acc[ii][jj] += p[ii] * vv[jj];
  }
#pragma unroll
  for (int ii = 0; ii < 4; ++ii) {
    int w = qi2 * 4 + ii;
    ushort4 o4 = make_ushort4(f2b(acc[ii][0]), f2b(acc[ii][1]),
                              f2b(acc[ii][2]), f2b(acc[ii][3]));
    *(ushort4*)(qc + ((size_t)(b * 4096 + s0 + w)) * 1024 + hoff + di * 4) = o4;
  }
}

// ---------------------------------------------------------------------------
extern "C" void kernel_launch(void* const* d_in, const int* in_sizes, int n_in,
                              void* d_out, int out_size, void* d_ws,
                              size_t ws_size, hipStream_t stream) {
  const float* query = (const float*)d_in[0];
  const float* Wq = (const float*)d_in[1];
  const float* bq = (const float*)d_in[2];
  const float* Wk = (const float*)d_in[3];
  const float* bk = (const float*)d_in[4];
  const float* Wv = (const float*)d_in[5];
  const float* bv = (const float*)d_in[6];
  const float* Wo = (const float*)d_in[7];
  const float* bo = (const float*)d_in[8];
  const float* g_l = (const float*)d_in[9];
  const float* b_l = (const float*)d_in[10];
  const float* g_s = (const float*)d_in[11];
  const float* b_s = (const float*)d_in[12];
  const float* Wd = (const float*)d_in[13];
  const float* bd = (const float*)d_in[14];
  float* out = (float*)d_out;

  // Workspace layout (~187 MB; proven bound >= 244.7 MB from R0-R2)
  unsigned short* qb = (unsigned short*)d_ws;  // 16,777,216 bf16 (Q, then C)
  unsigned short* kb = qb + 16777216;          // 16,777,216 bf16
  unsigned short* vb = kb + 16777216;          // 16,777,216 bf16
  unsigned short* xb = vb + 16777216;          // 16,777,216 bf16 (X)
  float* yd = (float*)(xb + 16777216);         // 8,388,608 fp32
  float* stats = yd + 8388608;                 // 4,096
  float* col_pm = stats + 4096;                // 32,768
  float* col_ps = col_pm + 32768;              // 32,768
  float* kc_part = col_ps + 32768;             // 1,048,576
  float* vc_part = kc_part + 1048576;          // 1,048,576
  float* kc_ln = vc_part + 1048576;            // 131,072
  float* vc_ln = kc_ln + 131072;               // 131,072
  unsigned short* wqT = (unsigned short*)(vc_ln + 131072);  // 1,048,576 each
  unsigned short* wkT = wqT + 1048576;
  unsigned short* wvT = wkT + 1048576;
  unsigned short* woT = wvT + 1048576;
  unsigned short* wdT = woT + 1048576;         // 524,288

  dim3 blk(256);
  // bf16 conversions
  conv_rows<<<16384, blk, 0, stream>>>(query, xb);
  conv_wT<<<dim3(32, 32), blk, 0, stream>>>(Wq, wqT, 1024);
  conv_wT<<<dim3(32, 32), blk, 0, stream>>>(Wk, wkT, 1024);
  conv_wT<<<dim3(32, 32), blk, 0, stream>>>(Wv, wvT, 1024);
  conv_wT<<<dim3(32, 32), blk, 0, stream>>>(Wo, woT, 1024);
  conv_wT<<<dim3(16, 32), blk, 0, stream>>>(Wd, wdT, 512);
  // MFMA projections (Q/K/V -> bf16 out, head-scores -> fp32 out)
  gemm_bf16<<<dim3(8, 128), blk, 0, stream>>>(xb, wqT, bq, qb, 1024, 0.125f, 2);
  gemm_bf16<<<dim3(8, 128), blk, 0, stream>>>(xb, wkT, bk, kb, 1024, 1.0f, 2);
  gemm_bf16<<<dim3(8, 128), blk, 0, stream>>>(xb, wvT, bv, vb, 1024, 1.0f, 2);
  gemm_bf16<<<dim3(4, 128), blk, 0, stream>>>(xb, wdT, bd, yd, 512, 1.0f, 0);
  // LN K, V (in-place bf16)
  ln_bf<<<16384, blk, 0, stream>>>(kb, g_l, b_l);
  ln_bf<<<16384, blk, 0, stream>>>(vb, g_l, b_l);
  // head-score softmax stats (two-phase, 512-block parallel)
  col_part<<<dim3(8, 4, 16), blk, 0, stream>>>(yd, col_pm, col_ps);
  col_combine<<<8, blk, 0, stream>>>(col_pm, col_ps, stats);
  // landmark compression + LN
  compress<<<dim3(8, 16, 4), blk, 0, stream>>>(yd, stats, kb, vb,
                                               kc_part, vc_part);
  ln_compress<<<128, blk, 0, stream>>>(kc_part, vc_part, g_s, b_s, kc_ln, vc_ln);
  // fused attention (bf16 C overwrites qb)
  attention<<<dim3(64, 16, 4), blk, 0, stream>>>(qb, kb, vb, kc_ln, vc_ln);
  // output projection (+ (b,s)->(s,b) remap), reads bf16 C directly
  gemm_bf16<<<dim3(8, 128), blk, 0, stream>>>(qb, woT, bo, out, 1024, 1.0f, 1);
}